// Round 15
// baseline (54.554 us; speedup 1.0000x reference)
//
#include <hip/hip_runtime.h>
#include <hip/hip_bf16.h>

#define IN_F 8192
#define OUT_F 8192
#define NROWS 128
#define CB 256
#define NSL 8                  // split-K slices
#define KSLICE (IN_F / NSL)    // 1024
#define NTB 128                // n-tile per block
#define QC (IN_F / 8)          // 1024 dwords per Qidxs row

using bf8    = __attribute__((ext_vector_type(8))) short;   // 8 bf16 (4 VGPRs)
using f32x16 = __attribute__((ext_vector_type(16))) float;  // 32x32 accum

typedef const __attribute__((address_space(1))) void* as1cv;
typedef __attribute__((address_space(3))) void* as3v;

__device__ inline float bf2f(unsigned int u) {
    union { unsigned int i; float f; } v; v.i = u << 16; return v.f;
}
__device__ inline unsigned short f2bf(float f) {
    __hip_bfloat16 h = __float2bfloat16(f);
    return *reinterpret_cast<unsigned short*>(&h);
}
__device__ inline void unpack8(uint4 v, float* f) {
    f[0] = bf2f(v.x & 0xffffu); f[1] = bf2f(v.x >> 16);
    f[2] = bf2f(v.y & 0xffffu); f[3] = bf2f(v.y >> 16);
    f[4] = bf2f(v.z & 0xffffu); f[5] = bf2f(v.z >> 16);
    f[6] = bf2f(v.w & 0xffffu); f[7] = bf2f(v.w >> 16);
}

#define FWHT_SCALE 0.011048543456039806f  // 1/sqrt(8192)

// ---------------- FWHT-4096 on 256 threads x 16 elems (round-11 proven) ----
#define FWHT16(v)                                                         \
    _Pragma("unroll")                                                     \
    for (int hb = 0; hb < 4; ++hb) {                                      \
        const int hh = 1 << hb;                                           \
        _Pragma("unroll")                                                 \
        for (int j = 0; j < 16; ++j)                                      \
            if (!(j & hh)) {                                              \
                float a_ = v[j], b_ = v[j | hh];                          \
                v[j] = a_ + b_; v[j | hh] = a_ - b_;                      \
            }                                                             \
    }

__device__ inline void fwht4096(float* v, float* lds, int t) {
    FWHT16(v)
#pragma unroll
    for (int e = 0; e < 16; ++e) lds[e * 260 + t] = v[e];
    __syncthreads();
    {
        const int base = (t & 15) * 260 + (t >> 4) * 16;
#pragma unroll
        for (int q = 0; q < 4; ++q) {
            float4 f = *reinterpret_cast<const float4*>(&lds[base + q * 4]);
            v[q * 4 + 0] = f.x; v[q * 4 + 1] = f.y;
            v[q * 4 + 2] = f.z; v[q * 4 + 3] = f.w;
        }
    }
    FWHT16(v)
    __syncthreads();
    {
        const int e = t & 15, ub = t >> 4;
#pragma unroll
        for (int i = 0; i < 16; ++i) lds[e * 260 + i * 16 + ub] = v[i];
    }
    __syncthreads();
    {
        const int e = t & 15, i = t >> 4;
#pragma unroll
        for (int ub = 0; ub < 16; ++ub) v[ub] = lds[e * 260 + i * 16 + ub];
    }
    FWHT16(v)
    __syncthreads();
    {
        const int e = t & 15, i = t >> 4;
#pragma unroll
        for (int ub = 0; ub < 16; ++ub) lds[ub * 260 + i * 16 + e] = v[ub];
    }
    __syncthreads();
    {
        const int base = (t >> 4) * 260 + (t & 15) * 16;
#pragma unroll
        for (int q = 0; q < 4; ++q) {
            float4 f = *reinterpret_cast<const float4*>(&lds[base + q * 4]);
            v[q * 4 + 0] = f.x; v[q * 4 + 1] = f.y;
            v[q * 4 + 2] = f.z; v[q * 4 + 3] = f.w;
        }
    }
}

// ---- Kernel A: xt = fwht(input/scaleWH*SU), tiled for 32x32x16 A-frags ----
// Layout: elem (R,K) at ((R>>5)*512 + (K>>4))*512 + ((K>>3)&1)*256
//         + (R&31)*8 + (K&7)   [ushort units]
// A wave frag (32 rows x 16 k) = one contiguous 1KB chunk (lane*16B).
__global__ __launch_bounds__(256) void k_pre5(const float* __restrict__ in,
                                              const float* __restrict__ scaleWH,
                                              const float* __restrict__ SU,
                                              unsigned short* __restrict__ xt) {
    __shared__ float lds[4160];
    const int r = blockIdx.x, h = blockIdx.y, t = threadIdx.x;
    float v[16];
    const float4* xp = reinterpret_cast<const float4*>(in + (size_t)r * IN_F);
    const float4* sp = reinterpret_cast<const float4*>(scaleWH);
    const float4* up = reinterpret_cast<const float4*>(SU);
#pragma unroll
    for (int q = 0; q < 4; ++q) {
        float4 xl = xp[t * 4 + q],        sl = sp[t * 4 + q],        ul = up[t * 4 + q];
        float4 xh = xp[1024 + t * 4 + q], sh = sp[1024 + t * 4 + q], uh = up[1024 + t * 4 + q];
        float lo0 = xl.x / sl.x * ul.x, hi0 = xh.x / sh.x * uh.x;
        float lo1 = xl.y / sl.y * ul.y, hi1 = xh.y / sh.y * uh.y;
        float lo2 = xl.z / sl.z * ul.z, hi2 = xh.z / sh.z * uh.z;
        float lo3 = xl.w / sl.w * ul.w, hi3 = xh.w / sh.w * uh.w;
        v[q * 4 + 0] = h ? lo0 - hi0 : lo0 + hi0;
        v[q * 4 + 1] = h ? lo1 - hi1 : lo1 + hi1;
        v[q * 4 + 2] = h ? lo2 - hi2 : lo2 + hi2;
        v[q * 4 + 3] = h ? lo3 - hi3 : lo3 + hi3;
    }
    fwht4096(v, lds, t);
    // thread holds k = k0 + e, k0 = h*4096 + (t>>4)*256 + (t&15)*16
    const int k0 = h * 4096 + (t >> 4) * 256 + (t & 15) * 16;
    const size_t base = ((size_t)(r >> 5) * 512 + (k0 >> 4)) * 512 + (size_t)(r & 31) * 8;
#pragma unroll
    for (int half = 0; half < 2; ++half) {
        unsigned int w[4];
#pragma unroll
        for (int p = 0; p < 4; ++p) {
            unsigned int lo = f2bf(v[half * 8 + 2 * p]     * FWHT_SCALE);
            unsigned int hi = f2bf(v[half * 8 + 2 * p + 1] * FWHT_SCALE);
            w[p] = lo | (hi << 16);
        }
        *reinterpret_cast<uint4*>(xt + base + half * 256) = make_uint4(w[0], w[1], w[2], w[3]);
    }
}

// ---- Kernel B: GEMM with mfma_32x32x16 — 2x FLOP/gather, 4x fewer gathers --
// grid (64, NSL); 256 thr = 4 waves, each wave = full M (4 m-blocks of 32)
// x 32 n-cols. Per iter (K=16): 1 q-read + 1 gather + 4 A-loads + 4 MFMA.
// Whole 64KB Qidxs slice in LDS, staged in 2 halves (half 1 in flight
// across half 0's 32 iterations); 2 barriers total.
__global__ __launch_bounds__(256, 2) void k_gemm12(
        const unsigned short* __restrict__ xt,
        const int* __restrict__ Qidxs,
        const float* __restrict__ cb,
        const float* __restrict__ wscale,
        unsigned short* __restrict__ pout) {
    __shared__ __align__(16) unsigned short cbl[CB][8];   // 4 KB
    __shared__ __align__(16) int Qlds[2][8192];           // 2 x 32 KB k-halves
    const int tid = threadIdx.x;
    const int wave = tid >> 6, lane = tid & 63;
    const int ln31 = lane & 31, lh = lane >> 5;
    const int n0 = blockIdx.x * NTB;
    const int ks0 = blockIdx.y * KSLICE;
    const int ksb2 = ks0 >> 4;          // 16-wide k-tile base
    const int c0 = ks0 >> 3;            // dword col base in Qidxs row

    // stage one 128-row x 64-dword half (32 KB); LDS dest linear per lane,
    // global col-group pre-swizzled by (row & 7) for clean in-loop reads.
    auto stageQ = [&](int h) {
#pragma unroll
        for (int j = 0; j < 8; ++j) {
            const int row = j * 16 + wave * 4 + (lane >> 4);
            const int cgs = (lane & 15) ^ (row & 7);
            const int* g = Qidxs + (size_t)(n0 + row) * QC + c0 + h * 64 + cgs * 4;
            as3v l = (as3v)(&Qlds[h][(j * 16 + wave * 4) * 64]);
            __builtin_amdgcn_global_load_lds((as1cv)(const void*)g, l, 16, 0, 0);
        }
    };

    stageQ(0);
    const float wsc = wscale[0];
    for (int e = tid; e < CB * 8; e += 256) cbl[e >> 3][e & 7] = f2bf(cb[e] * wsc);

    f32x16 acc[4];
#pragma unroll
    for (int mt = 0; mt < 4; ++mt)
#pragma unroll
        for (int r2 = 0; r2 < 16; ++r2) acc[mt][r2] = 0.f;

    // A base pointers per m-block (tiled layout; frag = 1KB at tile*1KB)
    const unsigned short* xw0 = xt + ((size_t)(0 * 512) + ksb2) * 512 + lane * 8;
    const unsigned short* xw1 = xt + ((size_t)(1 * 512) + ksb2) * 512 + lane * 8;
    const unsigned short* xw2 = xt + ((size_t)(2 * 512) + ksb2) * 512 + lane * 8;
    const unsigned short* xw3 = xt + ((size_t)(3 * 512) + ksb2) * 512 + lane * 8;

    const int qrow = wave * 32 + ln31;   // this lane's n-row within block
    const int qs7 = qrow & 7;
    const int qb = qrow * 64;

#define QR(H, ITL) (Qlds[H][qb + (((((ITL) * 2 + lh) >> 2) ^ qs7) << 2) + (((ITL) * 2 + lh) & 3)])
#define GA(Q) (*(const bf8*)&cbl[(Q)][0])
#define LA(D, IT) {                                                           \
        D##0 = *(const bf8*)(xw0 + (size_t)(IT) * 512);                       \
        D##1 = *(const bf8*)(xw1 + (size_t)(IT) * 512);                       \
        D##2 = *(const bf8*)(xw2 + (size_t)(IT) * 512);                       \
        D##3 = *(const bf8*)(xw3 + (size_t)(IT) * 512); }
#define MFMA4(A_, B_) {                                                       \
        acc[0] = __builtin_amdgcn_mfma_f32_32x32x16_bf16(A_##0, B_, acc[0], 0, 0, 0); \
        acc[1] = __builtin_amdgcn_mfma_f32_32x32x16_bf16(A_##1, B_, acc[1], 0, 0, 0); \
        acc[2] = __builtin_amdgcn_mfma_f32_32x32x16_bf16(A_##2, B_, acc[2], 0, 0, 0); \
        acc[3] = __builtin_amdgcn_mfma_f32_32x32x16_bf16(A_##3, B_, acc[3], 0, 0, 0); }

    // two-phase pipeline per half: q-reads ~2 iters ahead, gather 1 ahead,
    // A-loads 2 ahead; all names static, no copies.
#define CHUNK(H) {                                                            \
        int qE = QR(H, 0), qO = QR(H, 1);                                     \
        bf8 aE0, aE1, aE2, aE3, aO0, aO1, aO2, aO3;                           \
        LA(aE, (H) * 32 + 0) LA(aO, (H) * 32 + 1)                             \
        bf8 bE = GA(qE), bO;                                                  \
        _Pragma("unroll")                                                     \
        for (int i2 = 0; i2 < 16; ++i2) {                                     \
            const int itl = i2 * 2;                                           \
            if (i2 < 15) qE = QR(H, itl + 2);                                 \
            bO = GA(qO);                                                      \
            MFMA4(aE, bE)                                                     \
            if (i2 < 15) LA(aE, (H) * 32 + itl + 2)                           \
            if (i2 < 15) qO = QR(H, itl + 3);                                 \
            if (i2 < 15) bE = GA(qE);                                         \
            MFMA4(aO, bO)                                                     \
            if (i2 < 15) LA(aO, (H) * 32 + itl + 3)                           \
        } }

    __syncthreads();     // cbl + half 0 staged
    stageQ(1);           // half 1 in flight across half-0 compute (~32 iters)
    CHUNK(0)
    __syncthreads();     // drains stageQ(1) — issued a full half ago
    CHUNK(1)
#undef CHUNK
#undef MFMA4
#undef LA
#undef GA
#undef QR

    // epilogue: 32x32 C/D: col = lane&31, row = (reg&3)+8*(reg>>2)+4*lh
    unsigned short* ps = pout + (size_t)blockIdx.y * (NROWS * OUT_F);
    const int col = n0 + wave * 32 + ln31;
#pragma unroll
    for (int mt = 0; mt < 4; ++mt)
#pragma unroll
        for (int r2 = 0; r2 < 16; ++r2) {
            const int row = mt * 32 + (r2 & 3) + 8 * (r2 >> 2) + 4 * lh;
            ps[(size_t)row * OUT_F + col] = f2bf(acc[mt][r2]);
        }
}

// ---- Kernel C: out = fwht(sum_slices)*SV + bias, grid (128,2), f32 out ----
__global__ __launch_bounds__(256) void k_post4(const unsigned short* __restrict__ pin,
                                               const float* __restrict__ SV,
                                               const float* __restrict__ bias,
                                               float* __restrict__ out) {
    __shared__ float lds[4160];
    const int r = blockIdx.x, h = blockIdx.y, t = threadIdx.x;
    float lo[16], hi[16], v[16];
#pragma unroll
    for (int j = 0; j < 16; ++j) { lo[j] = 0.f; hi[j] = 0.f; }
#pragma unroll 1
    for (int sl = 0; sl < NSL; ++sl) {
        const uint4* pl = reinterpret_cast<const uint4*>(
            pin + (size_t)sl * NROWS * OUT_F + (size_t)r * OUT_F + t * 16);
        const uint4* ph = reinterpret_cast<const uint4*>(
            pin + (size_t)sl * NROWS * OUT_F + (size_t)r * OUT_F + 4096 + t * 16);
        float a[8], b[8];
        unpack8(pl[0], a); unpack8(pl[1], b);
#pragma unroll
        for (int j = 0; j < 8; ++j) { lo[j] += a[j]; lo[8 + j] += b[j]; }
        unpack8(ph[0], a); unpack8(ph[1], b);
#pragma unroll
        for (int j = 0; j < 8; ++j) { hi[j] += a[j]; hi[8 + j] += b[j]; }
    }
#pragma unroll
    for (int j = 0; j < 16; ++j) v[j] = h ? lo[j] - hi[j] : lo[j] + hi[j];
    fwht4096(v, lds, t);
    const int cb4 = (h * 4096 + (t >> 4) * 256 + (t & 15) * 16) >> 2;
    const float4* svp = reinterpret_cast<const float4*>(SV);
    const float4* bip = reinterpret_cast<const float4*>(bias);
    float4* op = reinterpret_cast<float4*>(out + (size_t)r * OUT_F);
#pragma unroll
    for (int q = 0; q < 4; ++q) {
        float4 sv = svp[cb4 + q], bi = bip[cb4 + q], o;
        o.x = v[q * 4 + 0] * FWHT_SCALE * sv.x + bi.x;
        o.y = v[q * 4 + 1] * FWHT_SCALE * sv.y + bi.y;
        o.z = v[q * 4 + 2] * FWHT_SCALE * sv.z + bi.z;
        o.w = v[q * 4 + 3] * FWHT_SCALE * sv.w + bi.w;
        op[cb4 + q] = o;
    }
}

extern "C" void kernel_launch(void* const* d_in, const int* in_sizes, int n_in,
                              void* d_out, int out_size, void* d_ws, size_t ws_size,
                              hipStream_t stream) {
    const float* in      = (const float*)d_in[0];
    const int*   Qidxs   = (const int*)d_in[1];
    const float* cb      = (const float*)d_in[2];
    const float* scaleWH = (const float*)d_in[3];
    const float* SU      = (const float*)d_in[4];
    const float* SV      = (const float*)d_in[5];
    const float* wscale  = (const float*)d_in[6];
    const float* bias    = (const float*)d_in[7];
    float* out = (float*)d_out;

    unsigned short* xt    = (unsigned short*)d_ws;                    // 2 MB (tiled)
    unsigned short* parts = (unsigned short*)((char*)d_ws
                            + (size_t)NROWS * IN_F * 2);              // 16 MB

    k_pre5<<<dim3(NROWS, 2), 256, 0, stream>>>(in, scaleWH, SU, xt);
    k_gemm12<<<dim3(OUT_F / NTB, NSL), 256, 0, stream>>>(xt, Qidxs, cb, wscale, parts);
    k_post4<<<dim3(NROWS, 2), 256, 0, stream>>>(parts, SV, bias, out);
}